// Round 16
// baseline (137.015 us; speedup 1.0000x reference)
//
#include <hip/hip_runtime.h>
#include <hip/hip_bf16.h>
#include <stdint.h>

typedef __bf16 bf16_t;
typedef __bf16 bf16x8 __attribute__((ext_vector_type(8)));
typedef __bf16 bf16x4v __attribute__((ext_vector_type(4)));
typedef float  f32x4  __attribute__((ext_vector_type(4)));
typedef float  f32x16 __attribute__((ext_vector_type(16)));
typedef unsigned int u32;
typedef u32 u32x4 __attribute__((ext_vector_type(4)));

#define NEG_BIG (-1e10f)
#define LOG2E 1.44269504f

// async global->LDS, 16B per lane; LDS dest = wave-uniform base + lane*16
__device__ __forceinline__ void load_lds16(const void* gsrc, void* ldst) {
  __builtin_amdgcn_global_load_lds(
      (__attribute__((address_space(1))) void*)(gsrc),
      (__attribute__((address_space(3))) void*)(ldst), 16, 0, 0);
}

__device__ __forceinline__ u32 cvt_pk_bf16(float lo, float hi) {
  u32 r;
  asm("v_cvt_pk_bf16_f32 %0, %1, %2" : "=v"(r) : "v"(lo), "v"(hi));
  return r;
}

// ---------------- 1) weight transpose + cast: W[k][n] -> Wt[n][k] bf16, 16B stores ----------------
__global__ __launch_bounds__(256) void k_wtrans(
    const float* __restrict__ wq, const float* __restrict__ wk,
    const float* __restrict__ wv, const float* __restrict__ wo,
    bf16_t* __restrict__ Wt, bf16_t* __restrict__ Wot)
{
  __shared__ float t[64][65];
  int bid = blockIdx.x;                 // [0,1024)
  int z = bid >> 8, rem = bid & 255;
  const float* src = z==0 ? wq : z==1 ? wk : z==2 ? wv : wo;
  bf16_t*      dst = z < 3 ? (Wt + (size_t)z*(1u<<20)) : Wot;
  int n0 = (rem & 15) << 6, k0 = (rem >> 4) << 6;
  int c = threadIdx.x & 63, rb = threadIdx.x >> 6;
  #pragma unroll
  for (int i = 0; i < 16; ++i) {
    int r = i*4 + rb;
    t[r][c] = src[(size_t)(k0 + r)*1024 + n0 + c];
  }
  __syncthreads();
  int n = threadIdx.x & 63, hq = threadIdx.x >> 6;
  #pragma unroll
  for (int j = 0; j < 2; ++j) {
    int kk = hq*2 + j;                  // 8-col chunk index
    bf16x8 vv;
    #pragma unroll
    for (int e = 0; e < 8; ++e) vv[e] = (bf16_t)t[kk*8 + e][n];
    *(bf16x8*)&dst[(size_t)(n0 + n)*1024 + k0 + kk*8] = vv;
  }
}

// ---------------- 3) FUSED QKV GEMM: A = (input + pos_emb) cast bf16 in-staging ----------------
// C(4096 x 3072) = A_z * Wt^T; 128x128, BK=64, single-buffered 2-barrier loop (R6 structure).
// A-side: synchronous reg-staging (fp32 loads -> add -> cvt -> swizzled ds_write_b128);
// B-side: global_load_lds with pre-swizzled source. Eliminates the k_prep pass entirely.
// Q pre-scaled by (1/8)*log2e (exp2-domain softmax); z==2 writes V transposed.
__global__ __launch_bounds__(256, 2) void k_gemm_qkv(
    const float* __restrict__ iq, const float* __restrict__ ikv,
    const float* __restrict__ pq, const float* __restrict__ pk, const float* __restrict__ pv,
    const bf16_t* __restrict__ Wt,
    const float* __restrict__ bq, const float* __restrict__ bk, const float* __restrict__ bv,
    bf16_t* __restrict__ Qo, bf16_t* __restrict__ Ko, bf16_t* __restrict__ Vt)
{
  const int L = blockIdx.x;                         // 768 = 8 XCD x 96
  const int w = (L & 7) * 96 + (L >> 3);
  const int bx = w & 7, by = (w >> 3) & 31, bz = w >> 8;
  const int bn = bz * 8 + bx;

  const float* Ain = bz==0 ? iq : ikv;
  const float* Pin = bz==0 ? pq : (bz==1 ? pk : pv);
  const float* bias = bz==0 ? bq : bz==1 ? bk : bv;

  __shared__ bf16_t As[128*64];
  __shared__ bf16_t Bs[128*64];

  const int tid = threadIdx.x, lane = tid & 63, wid = tid >> 6;
  const int wm = wid >> 1, wn = wid & 1;
  const int bm0 = by * 128;
  const int bn0g = bn * 128;                        // row of Wt (0..3071)
  const int g = lane >> 4, c = lane & 15;
  const int sr = lane >> 3, sch = lane & 7;

  f32x4 acc[4][4] = {};

  for (int kt = 0; kt < 16; ++kt) {
    const int kc0 = kt * 64;
    // B: async global->LDS (issue first; latency overlaps A reg-staging)
    #pragma unroll
    for (int i = 0; i < 4; ++i) {
      int r  = wid*32 + i*8 + sr;
      int ca = sch ^ (r & 7);
      load_lds16(Wt + (size_t)(bn0g + r)*1024 + kc0 + ca*8, &Bs[(wid*32 + i*8)*64]);
    }
    // A: fp32 loads -> add -> bf16 -> swizzled ds_write_b128 (write-XOR == read-XOR, rule 21)
    #pragma unroll
    for (int j = 0; j < 4; ++j) {
      int r = wid*32 + j*8 + sr;
      size_t off = (size_t)(bm0 + r)*1024 + kc0 + sch*8;
      f32x4 a0 = *(const f32x4*)&Ain[off], a1 = *(const f32x4*)&Ain[off + 4];
      f32x4 p0 = *(const f32x4*)&Pin[off], p1 = *(const f32x4*)&Pin[off + 4];
      bf16x8 vv;
      #pragma unroll
      for (int e = 0; e < 4; ++e) {
        vv[e]     = (bf16_t)(a0[e] + p0[e]);
        vv[e + 4] = (bf16_t)(a1[e] + p1[e]);
      }
      *(bf16x8*)&As[r*64 + (sch ^ (r & 7))*8] = vv;
    }
    __syncthreads();
    #pragma unroll
    for (int kk = 0; kk < 2; ++kk) {
      bf16x8 af[4], bfr[4];
      #pragma unroll
      for (int m = 0; m < 4; ++m) {
        int row = wm*64 + m*16 + c;
        int ch  = (kk*4 + g) ^ (row & 7);
        af[m] = *(const bf16x8*)&As[row*64 + ch*8];
      }
      #pragma unroll
      for (int n = 0; n < 4; ++n) {
        int row = wn*64 + n*16 + c;
        int ch  = (kk*4 + g) ^ (row & 7);
        bfr[n] = *(const bf16x8*)&Bs[row*64 + ch*8];
      }
      #pragma unroll
      for (int m = 0; m < 4; ++m)
        #pragma unroll
        for (int n = 0; n < 4; ++n)
          acc[m][n] = __builtin_amdgcn_mfma_f32_16x16x32_bf16(af[m], bfr[n], acc[m][n], 0, 0, 0);
    }
    __syncthreads();
  }

  if (bz < 2) {
    bf16_t* C = bz==0 ? Qo : Ko;
    const float scale = bz==0 ? 0.125f * LOG2E : 1.0f;
    #pragma unroll
    for (int n = 0; n < 4; ++n) {
      int col = (bn0g & 1023) + wn*64 + n*16 + c;
      float bn_ = bias[col];
      #pragma unroll
      for (int m = 0; m < 4; ++m) {
        int row0 = bm0 + wm*64 + m*16 + g*4;
        #pragma unroll
        for (int r = 0; r < 4; ++r)
          C[(size_t)(row0 + r)*1024 + col] = (bf16_t)((acc[m][n][r] + bn_) * scale);
      }
    }
  } else {
    // V panel: write transposed into Vt[(b*16+h)*64+hd][s]
    #pragma unroll
    for (int n = 0; n < 4; ++n) {
      int colz = (bn0g & 1023) + wn*64 + n*16 + c;  // h*64+hd
      float bn_ = bias[colz];
      int h = colz >> 6, hd = colz & 63;
      #pragma unroll
      for (int m = 0; m < 4; ++m) {
        int row0 = bm0 + wm*64 + m*16 + g*4;        // b*1024 + s0
        int b = row0 >> 10, s0 = row0 & 1023;
        bf16x4v v4;
        #pragma unroll
        for (int r = 0; r < 4; ++r) v4[r] = (bf16_t)(acc[m][n][r] + bn_);
        *(bf16x4v*)&Vt[(size_t)((b*16 + h)*64 + hd)*1024 + s0] = v4;
      }
    }
  }
}

// ---------------- 5) flash attention, swapped-QK^T, no-max exp2 softmax, SPLIT-KV x2 ----------------
__global__ __launch_bounds__(512, 4) void k_attn2(
    const bf16_t* __restrict__ Qm, const bf16_t* __restrict__ Km,
    const bf16_t* __restrict__ Vt, const float* __restrict__ mask,
    bf16_t* __restrict__ X2)
{
  __shared__ bf16_t Ks[2][2][64*64];  // [half][buf][kv][hd], chunk-swizzled
  __shared__ bf16_t Vs[2][2][64*64];  // [half][buf][hd][kv] (aliased as obuf in epilogue)
  __shared__ float  bias_lds[1024];   // (1-mask)*NEG_BIG*log2e for this batch
  __shared__ int    tflag[16];        // per-kv-tile "has any masked key" flag
  __shared__ float  l_lds[4][32];     // half-0 total l
  __shared__ float  l2_lds[4][32];    // half-1 partial l

  const int L = blockIdx.x;           // 512 = 8 XCD x 64
  const int kk_ = L >> 3;
  const int bh = (L & 7) * 8 + (kk_ >> 3);
  const int qt = kk_ & 7;
  const int b = bh >> 4, h = bh & 15;

  const int tid = threadIdx.x, lane = tid & 63, wid = tid >> 6;  // wid 0..7
  const int half = wid >> 2, w4 = wid & 3;
  const int lq = lane & 31;           // q column
  const int hi = lane >> 5;

  if (tid < 16) tflag[tid] = 0;
  __syncthreads();
  {
    float2 m2 = *(const float2*)&mask[b*1024 + tid*2];
    float2 b2;
    b2.x = (1.0f - m2.x) * (NEG_BIG * LOG2E);
    b2.y = (1.0f - m2.y) * (NEG_BIG * LOG2E);
    *(float2*)&bias_lds[tid*2] = b2;
    if (b2.x != 0.f || b2.y != 0.f)
      tflag[tid >> 5] = 1;            // tile kt covers mask idx [kt*64, kt*64+64)
  }

  const int q0w = qt*128 + w4*32;
  bf16x8 qf[4];
  #pragma unroll
  for (int kb = 0; kb < 4; ++kb)
    qf[kb] = *(const bf16x8*)&Qm[(size_t)(b*1024 + q0w + lq)*1024 + h*64 + kb*16 + hi*8];

  f32x16 oacc[2] = {};
  float lsum = 0.f;

  const int sr8 = (lane >> 3);
  const int sc8 = lane & 7;
  #define STAGE(bufi, kv0)                                                        \
    {                                                                             \
      _Pragma("unroll")                                                           \
      for (int cc = 0; cc < 2; ++cc) {                                            \
        int r  = cc*32 + w4*8 + sr8;                                              \
        int ca = sc8 ^ (r & 7);                                                   \
        load_lds16(Km + (size_t)(b*1024 + (kv0) + r)*1024 + h*64 + ca*8,          \
                   &Ks[half][bufi][(cc*32 + w4*8)*64]);                           \
        load_lds16(Vt + (size_t)((b*16 + h)*64 + r)*1024 + (kv0) + ca*8,          \
                   &Vs[half][bufi][(cc*32 + w4*8)*64]);                           \
      }                                                                           \
    }

  STAGE(0, half*512);
  __syncthreads();                    // publishes stage 0 (both halves), bias_lds, tflag

  for (int t = 0; t < 8; ++t) {
    const int kt = half*8 + t;
    const int buf = t & 1;
    if (t < 7) STAGE(buf ^ 1, (kt + 1) * 64);

    f32x16 s[2];
    __builtin_amdgcn_s_setprio(1);
    #pragma unroll
    for (int blk = 0; blk < 2; ++blk) {
      f32x16 acc = {};
      #pragma unroll
      for (int kb = 0; kb < 4; ++kb) {
        int row = blk*32 + lq;
        int ch  = (kb*2 + hi) ^ (row & 7);
        bf16x8 kf = *(const bf16x8*)&Ks[half][buf][row*64 + ch*8];
        acc = __builtin_amdgcn_mfma_f32_32x32x16_bf16(kf, qf[kb], acc, 0, 0, 0);
      }
      s[blk] = acc;
    }
    __builtin_amdgcn_s_setprio(0);

    if (tflag[kt]) {                  // wave-uniform; skipped when tile has no masked keys
      #pragma unroll
      for (int blk = 0; blk < 2; ++blk)
        #pragma unroll
        for (int g2 = 0; g2 < 4; ++g2) {
          float4 b4 = *(const float4*)&bias_lds[kt*64 + blk*32 + g2*8 + hi*4];
          s[blk][g2*4+0] += b4.x;
          s[blk][g2*4+1] += b4.y;
          s[blk][g2*4+2] += b4.z;
          s[blk][g2*4+3] += b4.w;
        }
    }

    // no-max softmax: P = exp2(min(s, 60)); masked -> exp2(-1.4e10) = 0 exactly.
    #pragma unroll
    for (int blk = 0; blk < 2; ++blk)
      #pragma unroll
      for (int r = 0; r < 16; ++r) {
        float sv = fminf(s[blk][r], 60.0f);
        asm("v_exp_f32 %0, %1" : "=v"(sv) : "v"(sv));
        s[blk][r] = sv;
      }

    // pairwise tree-sum of the 32 P values (depth 5)
    float ts[8];
    #pragma unroll
    for (int r = 0; r < 8; ++r)
      ts[r] = (s[0][r] + s[0][r+8]) + (s[1][r] + s[1][r+8]);
    float s0 = (ts[0] + ts[1]) + (ts[2] + ts[3]);
    float s1 = (ts[4] + ts[5]) + (ts[6] + ts[7]);
    float rsum = s0 + s1;
    lsum += rsum + __shfl_xor(rsum, 32, 64);

    // P -> bf16 A-fragments in-register (T12)
    u32 paw[4][4];
    #pragma unroll
    for (int blk = 0; blk < 2; ++blk)
      #pragma unroll
      for (int hf = 0; hf < 2; ++hf) {
        int base = hf * 8;
        #pragma unroll
        for (int w2 = 0; w2 < 2; ++w2) {
          u32 x = cvt_pk_bf16(s[blk][base + 2*w2],     s[blk][base + 2*w2 + 1]);
          u32 y = cvt_pk_bf16(s[blk][base + 4 + 2*w2], s[blk][base + 4 + 2*w2 + 1]);
          asm("v_permlane32_swap_b32 %0, %1" : "+v"(x), "+v"(y));
          paw[blk*2 + hf][w2]     = x;
          paw[blk*2 + hf][w2 + 2] = y;
        }
      }

    __builtin_amdgcn_s_setprio(1);
    #pragma unroll
    for (int ks = 0; ks < 4; ++ks) {
      u32x4 t2 = { paw[ks][0], paw[ks][1], paw[ks][2], paw[ks][3] };
      bf16x8 pa = __builtin_bit_cast(bf16x8, t2);
      #pragma unroll
      for (int nb = 0; nb < 2; ++nb) {
        int row = nb*32 + lq;
        int ch  = (ks*2 + hi) ^ (row & 7);
        bf16x8 vf = *(const bf16x8*)&Vs[half][buf][row*64 + ch*8];
        oacc[nb] = __builtin_amdgcn_mfma_f32_32x32x16_bf16(pa, vf, oacc[nb], 0, 0, 0);
      }
    }
    __builtin_amdgcn_s_setprio(0);
    __syncthreads();
  }
  #undef STAGE

  // ---- combine halves: l = l0+l1, O = O0+O1 (un-normalized partials share scale) ----
  float* obuf = (float*)&Vs[0][0][0];   // 32 KB, Vs is dead now
  // obuf layout: [w4][hi][reg(16)][nb(2)][lq(32)]
  if (half == 1) {
    l2_lds[w4][lq] = lsum;              // lanes hi=0/1 write same value (both hold l[q=lq])
    #pragma unroll
    for (int nb = 0; nb < 2; ++nb)
      #pragma unroll
      for (int reg = 0; reg < 16; ++reg)
        obuf[((((w4*2 + hi)*16 + reg)*2) + nb)*32 + lq] = oacc[nb][reg];
  }
  __syncthreads();
  if (half == 0) {
    float lt = lsum + l2_lds[w4][lq];
    l_lds[w4][lq] = lt;
  }
  __syncthreads();
  if (half == 0) {
    #pragma unroll
    for (int g2 = 0; g2 < 4; ++g2)
      #pragma unroll
      for (int j = 0; j < 4; ++j) {
        int reg  = g2*4 + j;
        int qrow = j + 8*g2 + 4*hi;
        float inv = 1.0f / l_lds[w4][qrow];
        #pragma unroll
        for (int nb = 0; nb < 2; ++nb) {
          float o = oacc[nb][reg] + obuf[((((w4*2 + hi)*16 + reg)*2) + nb)*32 + lq];
          X2[(size_t)(b*1024 + q0w + qrow)*1024 + h*64 + nb*32 + lq] = (bf16_t)(o * inv);
        }
      }
  }
}

// ---------------- 6) output GEMM: out = X2 * Wot^T + bo (fp32), single-buffered ----------------
__global__ __launch_bounds__(256, 3) void k_gemm_out(
    const bf16_t* __restrict__ A, const bf16_t* __restrict__ Bt,
    const float* __restrict__ bo, float* __restrict__ C)
{
  const int L = blockIdx.x;                 // 256 = 8 XCD x 32
  const int w = (L & 7) * 32 + (L >> 3);
  const int bx = w & 7, by = w >> 3;

  __shared__ bf16_t As[128*64];
  __shared__ bf16_t Bs[128*64];

  const int tid = threadIdx.x, lane = tid & 63, wid = tid >> 6;
  const int wm = wid >> 1, wn = wid & 1;
  const int bm0 = by * 128, bn0 = bx * 128;
  const int g = lane >> 4, c = lane & 15;
  const int sr = lane >> 3, sch = lane & 7;

  f32x4 acc[4][4] = {};

  #define STAGEO(kt_)                                                            \
    { _Pragma("unroll")                                                          \
      for (int i = 0; i < 4; ++i) {                                              \
        int r  = wid*32 + i*8 + sr;                                              \
        int ca = sch ^ (r & 7);                                                  \
        load_lds16(A  + (size_t)(bm0 + r)*1024 + (size_t)(kt_)*64 + ca*8,        \
                   &As[(wid*32 + i*8)*64]);                                      \
        load_lds16(Bt + (size_t)(bn0 + r)*1024 + (size_t)(kt_)*64 + ca*8,        \
                   &Bs[(wid*32 + i*8)*64]);                                      \
      } }

  for (int kt = 0; kt < 16; ++kt) {
    STAGEO(kt);
    __syncthreads();
    #pragma unroll
    for (int kk = 0; kk < 2; ++kk) {
      bf16x8 af[4], bfr[4];
      #pragma unroll
      for (int m = 0; m < 4; ++m) {
        int row = wm*64 + m*16 + c;
        int ch  = (kk*4 + g) ^ (row & 7);
        af[m] = *(const bf16x8*)&As[row*64 + ch*8];
      }
      #pragma unroll
      for (int n = 0; n < 4; ++n) {
        int row = wn*64 + n*16 + c;
        int ch  = (kk*4 + g) ^ (row & 7);
        bfr[n] = *(const bf16x8*)&Bs[row*64 + ch*8];
      }
      #pragma unroll
      for (int m = 0; m < 4; ++m)
        #pragma unroll
        for (int n = 0; n < 4; ++n)
          acc[m][n] = __builtin_amdgcn_mfma_f32_16x16x32_bf16(af[m], bfr[n], acc[m][n], 0, 0, 0);
    }
    __syncthreads();
  }
  #undef STAGEO

  #pragma unroll
  for (int n = 0; n < 4; ++n) {
    int col = bn0 + wn*64 + n*16 + c;
    float bn_ = bo[col];
    #pragma unroll
    for (int m = 0; m < 4; ++m) {
      int row0 = bm0 + wm*64 + m*16 + g*4;
      #pragma unroll
      for (int r = 0; r < 4; ++r)
        C[(size_t)(row0 + r)*1024 + col] = acc[m][n][r] + bn_;
    }
  }
}

extern "C" void kernel_launch(void* const* d_in, const int* in_sizes, int n_in,
                              void* d_out, int out_size, void* d_ws, size_t ws_size,
                              hipStream_t stream) {
  const float* iq   = (const float*)d_in[0];
  const float* ikv  = (const float*)d_in[1];
  const float* pq   = (const float*)d_in[2];
  const float* pk   = (const float*)d_in[3];
  const float* pv   = (const float*)d_in[4];
  const float* mask = (const float*)d_in[5];
  const float* wq   = (const float*)d_in[6];
  const float* bq   = (const float*)d_in[7];
  const float* wk   = (const float*)d_in[8];
  const float* bk   = (const float*)d_in[9];
  const float* wv   = (const float*)d_in[10];
  const float* bv   = (const float*)d_in[11];
  const float* wo   = (const float*)d_in[12];
  const float* bo   = (const float*)d_in[13];
  float* out = (float*)d_out;

  char* ws = (char*)d_ws;
  bf16_t* Wt  = (bf16_t*)(ws + (size_t)(24u<<20));   // Wqt|Wkt|Wvt contiguous (3072 x 1024)
  bf16_t* Wot = (bf16_t*)(ws + (size_t)(30u<<20));
  bf16_t* Q   = (bf16_t*)(ws + (size_t)(32u<<20));
  bf16_t* K   = (bf16_t*)(ws + (size_t)(40u<<20));
  bf16_t* Vt  = (bf16_t*)(ws + (size_t)(56u<<20));
  bf16_t* X2  = (bf16_t*)(ws + (size_t)(64u<<20));

  k_wtrans<<<1024, 256, 0, stream>>>(wq, wk, wv, wo, Wt, Wot);
  k_gemm_qkv<<<768, 256, 0, stream>>>(iq, ikv, pq, pk, pv, Wt, bq, bk, bv, Q, K, Vt);
  k_attn2<<<512, 512, 0, stream>>>(Q, K, Vt, mask, X2);
  k_gemm_out<<<256, 256, 0, stream>>>(X2, Wot, bo, out);
}

// Round 17
// 110.518 us; speedup vs baseline: 1.2398x; 1.2398x over previous
//
#include <hip/hip_runtime.h>
#include <hip/hip_bf16.h>
#include <stdint.h>

typedef __bf16 bf16_t;
typedef __bf16 bf16x8 __attribute__((ext_vector_type(8)));
typedef __bf16 bf16x4v __attribute__((ext_vector_type(4)));
typedef float  f32x4  __attribute__((ext_vector_type(4)));
typedef float  f32x16 __attribute__((ext_vector_type(16)));
typedef unsigned int u32;
typedef u32 u32x4 __attribute__((ext_vector_type(4)));

#define NEG_BIG (-1e10f)
#define LOG2E 1.44269504f

// async global->LDS, 16B per lane; LDS dest = wave-uniform base + lane*16
__device__ __forceinline__ void load_lds16(const void* gsrc, void* ldst) {
  __builtin_amdgcn_global_load_lds(
      (__attribute__((address_space(1))) void*)(gsrc),
      (__attribute__((address_space(3))) void*)(ldst), 16, 0, 0);
}

__device__ __forceinline__ u32 cvt_pk_bf16(float lo, float hi) {
  u32 r;
  asm("v_cvt_pk_bf16_f32 %0, %1, %2" : "=v"(r) : "v"(lo), "v"(hi));
  return r;
}

// ---------------- 1a) stream prep: X = (input + pos_emb) -> bf16; ALL loads issued before use ----------------
// R15 post-mortem: VGPR=24 forced the compiler to serialize the 10 loads into ~3 latency
// batches (2.06 TB/s). sched_barrier(0) after the load pack pins all 10 in flight (1 batch).
__global__ __launch_bounds__(256) void k_prep(
    const float* __restrict__ iq, const float* __restrict__ ikv,
    const float* __restrict__ pq, const float* __restrict__ pk, const float* __restrict__ pv,
    bf16_t* __restrict__ Xq, bf16_t* __restrict__ Xk, bf16_t* __restrict__ Xv)
{
  size_t t0 = (size_t)blockIdx.x * 256 + threadIdx.x;   // 0..524287
  size_t f4 = t0 * 2;
  f32x4 a0  = ((const f32x4*)iq)[f4],  a1  = ((const f32x4*)iq)[f4+1];
  f32x4 b0  = ((const f32x4*)ikv)[f4], b1  = ((const f32x4*)ikv)[f4+1];
  f32x4 eq0 = ((const f32x4*)pq)[f4],  eq1 = ((const f32x4*)pq)[f4+1];
  f32x4 ek0 = ((const f32x4*)pk)[f4],  ek1 = ((const f32x4*)pk)[f4+1];
  f32x4 ev0 = ((const f32x4*)pv)[f4],  ev1 = ((const f32x4*)pv)[f4+1];
  __builtin_amdgcn_sched_barrier(0);    // pin: all 10 loads issued before any consumer
  bf16x8 q, k, v;
  #pragma unroll
  for (int e = 0; e < 4; ++e) {
    q[e] = (bf16_t)(a0[e] + eq0[e]); q[e+4] = (bf16_t)(a1[e] + eq1[e]);
    k[e] = (bf16_t)(b0[e] + ek0[e]); k[e+4] = (bf16_t)(b1[e] + ek1[e]);
    v[e] = (bf16_t)(b0[e] + ev0[e]); v[e+4] = (bf16_t)(b1[e] + ev1[e]);
  }
  *(bf16x8*)&Xq[t0*8] = q;
  *(bf16x8*)&Xk[t0*8] = k;
  *(bf16x8*)&Xv[t0*8] = v;
}

// ---------------- 1b) weight transpose + cast: W[k][n] -> Wt[n][k] bf16, 16B stores ----------------
__global__ __launch_bounds__(256) void k_wtrans(
    const float* __restrict__ wq, const float* __restrict__ wk,
    const float* __restrict__ wv, const float* __restrict__ wo,
    bf16_t* __restrict__ Wt, bf16_t* __restrict__ Wot)
{
  __shared__ float t[64][65];
  int bid = blockIdx.x;                 // [0,1024)
  int z = bid >> 8, rem = bid & 255;
  const float* src = z==0 ? wq : z==1 ? wk : z==2 ? wv : wo;
  bf16_t*      dst = z < 3 ? (Wt + (size_t)z*(1u<<20)) : Wot;
  int n0 = (rem & 15) << 6, k0 = (rem >> 4) << 6;
  int c = threadIdx.x & 63, rb = threadIdx.x >> 6;
  #pragma unroll
  for (int i = 0; i < 16; ++i) {
    int r = i*4 + rb;
    t[r][c] = src[(size_t)(k0 + r)*1024 + n0 + c];
  }
  __syncthreads();
  int n = threadIdx.x & 63, hq = threadIdx.x >> 6;
  #pragma unroll
  for (int j = 0; j < 2; ++j) {
    int kk = hq*2 + j;                  // 8-col chunk index
    bf16x8 vv;
    #pragma unroll
    for (int e = 0; e < 8; ++e) vv[e] = (bf16_t)t[kk*8 + e][n];
    *(bf16x8*)&dst[(size_t)(n0 + n)*1024 + k0 + kk*8] = vv;
  }
}

// ---------------- 3) QKV GEMM: C(4096 x 3072) = A_z * Wt^T; 128x128, BK=64 (R6/R14 proven form) ----------------
// Q is pre-scaled by (1/8)*log2e so the attention softmax can run in exp2 domain.
__global__ __launch_bounds__(256, 3) void k_gemm_qkv(
    const bf16_t* __restrict__ Xq, const bf16_t* __restrict__ Xk, const bf16_t* __restrict__ Xv,
    const bf16_t* __restrict__ Wt,
    const float* __restrict__ bq, const float* __restrict__ bk, const float* __restrict__ bv,
    bf16_t* __restrict__ Qo, bf16_t* __restrict__ Ko, bf16_t* __restrict__ Vt)
{
  const int L = blockIdx.x;                         // 768 = 8 XCD x 96
  const int w = (L & 7) * 96 + (L >> 3);
  const int bx = w & 7, by = (w >> 3) & 31, bz = w >> 8;
  const int bn = bz * 8 + bx;

  const bf16_t* A = bz==0 ? Xq : bz==1 ? Xk : Xv;
  const float* bias = bz==0 ? bq : bz==1 ? bk : bv;

  __shared__ bf16_t As[128*64];
  __shared__ bf16_t Bs[128*64];

  const int tid = threadIdx.x, lane = tid & 63, wid = tid >> 6;
  const int wm = wid >> 1, wn = wid & 1;
  const int bm0 = by * 128;
  const int bn0g = bn * 128;                        // row of Wt (0..3071)
  const int g = lane >> 4, c = lane & 15;
  const int sr = lane >> 3, sch = lane & 7;

  f32x4 acc[4][4] = {};

  #define STAGE(kt_)                                                             \
    { _Pragma("unroll")                                                          \
      for (int i = 0; i < 4; ++i) {                                              \
        int r  = wid*32 + i*8 + sr;                                              \
        int ca = sch ^ (r & 7);                                                  \
        load_lds16(A  + (size_t)(bm0  + r)*1024 + (size_t)(kt_)*64 + ca*8,       \
                   &As[(wid*32 + i*8)*64]);                                      \
        load_lds16(Wt + (size_t)(bn0g + r)*1024 + (size_t)(kt_)*64 + ca*8,       \
                   &Bs[(wid*32 + i*8)*64]);                                      \
      } }

  for (int kt = 0; kt < 16; ++kt) {
    STAGE(kt);
    __syncthreads();
    #pragma unroll
    for (int kk = 0; kk < 2; ++kk) {
      bf16x8 af[4], bfr[4];
      #pragma unroll
      for (int m = 0; m < 4; ++m) {
        int row = wm*64 + m*16 + c;
        int ch  = (kk*4 + g) ^ (row & 7);
        af[m] = *(const bf16x8*)&As[row*64 + ch*8];
      }
      #pragma unroll
      for (int n = 0; n < 4; ++n) {
        int row = wn*64 + n*16 + c;
        int ch  = (kk*4 + g) ^ (row & 7);
        bfr[n] = *(const bf16x8*)&Bs[row*64 + ch*8];
      }
      #pragma unroll
      for (int m = 0; m < 4; ++m)
        #pragma unroll
        for (int n = 0; n < 4; ++n)
          acc[m][n] = __builtin_amdgcn_mfma_f32_16x16x32_bf16(af[m], bfr[n], acc[m][n], 0, 0, 0);
    }
    __syncthreads();
  }
  #undef STAGE

  if (bz < 2) {
    bf16_t* C = bz==0 ? Qo : Ko;
    const float scale = bz==0 ? 0.125f * LOG2E : 1.0f;
    #pragma unroll
    for (int n = 0; n < 4; ++n) {
      int col = (bn0g & 1023) + wn*64 + n*16 + c;
      float bn_ = bias[col];
      #pragma unroll
      for (int m = 0; m < 4; ++m) {
        int row0 = bm0 + wm*64 + m*16 + g*4;
        #pragma unroll
        for (int r = 0; r < 4; ++r)
          C[(size_t)(row0 + r)*1024 + col] = (bf16_t)((acc[m][n][r] + bn_) * scale);
      }
    }
  } else {
    // V panel: write transposed into Vt[(b*16+h)*64+hd][s]
    #pragma unroll
    for (int n = 0; n < 4; ++n) {
      int colz = (bn0g & 1023) + wn*64 + n*16 + c;  // h*64+hd
      float bn_ = bias[colz];
      int h = colz >> 6, hd = colz & 63;
      #pragma unroll
      for (int m = 0; m < 4; ++m) {
        int row0 = bm0 + wm*64 + m*16 + g*4;        // b*1024 + s0
        int b = row0 >> 10, s0 = row0 & 1023;
        bf16x4v v4;
        #pragma unroll
        for (int r = 0; r < 4; ++r) v4[r] = (bf16_t)(acc[m][n][r] + bn_);
        *(bf16x4v*)&Vt[(size_t)((b*16 + h)*64 + hd)*1024 + s0] = v4;
      }
    }
  }
}

// ---------------- 5) flash attention, swapped-QK^T, no-max exp2 softmax, SPLIT-KV x2 ----------------
__global__ __launch_bounds__(512, 4) void k_attn2(
    const bf16_t* __restrict__ Qm, const bf16_t* __restrict__ Km,
    const bf16_t* __restrict__ Vt, const float* __restrict__ mask,
    bf16_t* __restrict__ X2)
{
  __shared__ bf16_t Ks[2][2][64*64];  // [half][buf][kv][hd], chunk-swizzled
  __shared__ bf16_t Vs[2][2][64*64];  // [half][buf][hd][kv] (aliased as obuf in epilogue)
  __shared__ float  bias_lds[1024];   // (1-mask)*NEG_BIG*log2e for this batch
  __shared__ int    tflag[16];        // per-kv-tile "has any masked key" flag
  __shared__ float  l_lds[4][32];     // half-0 total l
  __shared__ float  l2_lds[4][32];    // half-1 partial l

  const int L = blockIdx.x;           // 512 = 8 XCD x 64
  const int kk_ = L >> 3;
  const int bh = (L & 7) * 8 + (kk_ >> 3);
  const int qt = kk_ & 7;
  const int b = bh >> 4, h = bh & 15;

  const int tid = threadIdx.x, lane = tid & 63, wid = tid >> 6;  // wid 0..7
  const int half = wid >> 2, w4 = wid & 3;
  const int lq = lane & 31;           // q column
  const int hi = lane >> 5;

  if (tid < 16) tflag[tid] = 0;
  __syncthreads();
  {
    float2 m2 = *(const float2*)&mask[b*1024 + tid*2];
    float2 b2;
    b2.x = (1.0f - m2.x) * (NEG_BIG * LOG2E);
    b2.y = (1.0f - m2.y) * (NEG_BIG * LOG2E);
    *(float2*)&bias_lds[tid*2] = b2;
    if (b2.x != 0.f || b2.y != 0.f)
      tflag[tid >> 5] = 1;            // tile kt covers mask idx [kt*64, kt*64+64)
  }

  const int q0w = qt*128 + w4*32;
  bf16x8 qf[4];
  #pragma unroll
  for (int kb = 0; kb < 4; ++kb)
    qf[kb] = *(const bf16x8*)&Qm[(size_t)(b*1024 + q0w + lq)*1024 + h*64 + kb*16 + hi*8];

  f32x16 oacc[2] = {};
  float lsum = 0.f;

  const int sr8 = (lane >> 3);
  const int sc8 = lane & 7;
  #define STAGE(bufi, kv0)                                                        \
    {                                                                             \
      _Pragma("unroll")                                                           \
      for (int cc = 0; cc < 2; ++cc) {                                            \
        int r  = cc*32 + w4*8 + sr8;                                              \
        int ca = sc8 ^ (r & 7);                                                   \
        load_lds16(Km + (size_t)(b*1024 + (kv0) + r)*1024 + h*64 + ca*8,          \
                   &Ks[half][bufi][(cc*32 + w4*8)*64]);                           \
        load_lds16(Vt + (size_t)((b*16 + h)*64 + r)*1024 + (kv0) + ca*8,          \
                   &Vs[half][bufi][(cc*32 + w4*8)*64]);                           \
      }                                                                           \
    }

  STAGE(0, half*512);
  __syncthreads();                    // publishes stage 0 (both halves), bias_lds, tflag

  for (int t = 0; t < 8; ++t) {
    const int kt = half*8 + t;
    const int buf = t & 1;
    if (t < 7) STAGE(buf ^ 1, (kt + 1) * 64);

    f32x16 s[2];
    __builtin_amdgcn_s_setprio(1);
    #pragma unroll
    for (int blk = 0; blk < 2; ++blk) {
      f32x16 acc = {};
      #pragma unroll
      for (int kb = 0; kb < 4; ++kb) {
        int row = blk*32 + lq;
        int ch  = (kb*2 + hi) ^ (row & 7);
        bf16x8 kf = *(const bf16x8*)&Ks[half][buf][row*64 + ch*8];
        acc = __builtin_amdgcn_mfma_f32_32x32x16_bf16(kf, qf[kb], acc, 0, 0, 0);
      }
      s[blk] = acc;
    }
    __builtin_amdgcn_s_setprio(0);

    if (tflag[kt]) {                  // wave-uniform; skipped when tile has no masked keys
      #pragma unroll
      for (int blk = 0; blk < 2; ++blk)
        #pragma unroll
        for (int g2 = 0; g2 < 4; ++g2) {
          float4 b4 = *(const float4*)&bias_lds[kt*64 + blk*32 + g2*8 + hi*4];
          s[blk][g2*4+0] += b4.x;
          s[blk][g2*4+1] += b4.y;
          s[blk][g2*4+2] += b4.z;
          s[blk][g2*4+3] += b4.w;
        }
    }

    // no-max softmax: P = exp2(min(s, 60)); masked -> exp2(-1.4e10) = 0 exactly.
    #pragma unroll
    for (int blk = 0; blk < 2; ++blk)
      #pragma unroll
      for (int r = 0; r < 16; ++r) {
        float sv = fminf(s[blk][r], 60.0f);
        asm("v_exp_f32 %0, %1" : "=v"(sv) : "v"(sv));
        s[blk][r] = sv;
      }

    // pairwise tree-sum of the 32 P values (depth 5)
    float ts[8];
    #pragma unroll
    for (int r = 0; r < 8; ++r)
      ts[r] = (s[0][r] + s[0][r+8]) + (s[1][r] + s[1][r+8]);
    float s0 = (ts[0] + ts[1]) + (ts[2] + ts[3]);
    float s1 = (ts[4] + ts[5]) + (ts[6] + ts[7]);
    float rsum = s0 + s1;
    lsum += rsum + __shfl_xor(rsum, 32, 64);

    // P -> bf16 A-fragments in-register (T12)
    u32 paw[4][4];
    #pragma unroll
    for (int blk = 0; blk < 2; ++blk)
      #pragma unroll
      for (int hf = 0; hf < 2; ++hf) {
        int base = hf * 8;
        #pragma unroll
        for (int w2 = 0; w2 < 2; ++w2) {
          u32 x = cvt_pk_bf16(s[blk][base + 2*w2],     s[blk][base + 2*w2 + 1]);
          u32 y = cvt_pk_bf16(s[blk][base + 4 + 2*w2], s[blk][base + 4 + 2*w2 + 1]);
          asm("v_permlane32_swap_b32 %0, %1" : "+v"(x), "+v"(y));
          paw[blk*2 + hf][w2]     = x;
          paw[blk*2 + hf][w2 + 2] = y;
        }
      }

    __builtin_amdgcn_s_setprio(1);
    #pragma unroll
    for (int ks = 0; ks < 4; ++ks) {
      u32x4 t2 = { paw[ks][0], paw[ks][1], paw[ks][2], paw[ks][3] };
      bf16x8 pa = __builtin_bit_cast(bf16x8, t2);
      #pragma unroll
      for (int nb = 0; nb < 2; ++nb) {
        int row = nb*32 + lq;
        int ch  = (ks*2 + hi) ^ (row & 7);
        bf16x8 vf = *(const bf16x8*)&Vs[half][buf][row*64 + ch*8];
        oacc[nb] = __builtin_amdgcn_mfma_f32_32x32x16_bf16(pa, vf, oacc[nb], 0, 0, 0);
      }
    }
    __builtin_amdgcn_s_setprio(0);
    __syncthreads();
  }
  #undef STAGE

  // ---- combine halves: l = l0+l1, O = O0+O1 (un-normalized partials share scale) ----
  float* obuf = (float*)&Vs[0][0][0];   // 32 KB, Vs is dead now
  // obuf layout: [w4][hi][reg(16)][nb(2)][lq(32)]
  if (half == 1) {
    l2_lds[w4][lq] = lsum;              // lanes hi=0/1 write same value (both hold l[q=lq])
    #pragma unroll
    for (int nb = 0; nb < 2; ++nb)
      #pragma unroll
      for (int reg = 0; reg < 16; ++reg)
        obuf[((((w4*2 + hi)*16 + reg)*2) + nb)*32 + lq] = oacc[nb][reg];
  }
  __syncthreads();
  if (half == 0) {
    float lt = lsum + l2_lds[w4][lq];
    l_lds[w4][lq] = lt;
  }
  __syncthreads();
  if (half == 0) {
    #pragma unroll
    for (int g2 = 0; g2 < 4; ++g2)
      #pragma unroll
      for (int j = 0; j < 4; ++j) {
        int reg  = g2*4 + j;
        int qrow = j + 8*g2 + 4*hi;
        float inv = 1.0f / l_lds[w4][qrow];
        #pragma unroll
        for (int nb = 0; nb < 2; ++nb) {
          float o = oacc[nb][reg] + obuf[((((w4*2 + hi)*16 + reg)*2) + nb)*32 + lq];
          X2[(size_t)(b*1024 + q0w + qrow)*1024 + h*64 + nb*32 + lq] = (bf16_t)(o * inv);
        }
      }
  }
}

// ---------------- 6) output GEMM: out = X2 * Wot^T + bo (fp32), single-buffered ----------------
__global__ __launch_bounds__(256, 3) void k_gemm_out(
    const bf16_t* __restrict__ A, const bf16_t* __restrict__ Bt,
    const float* __restrict__ bo, float* __restrict__ C)
{
  const int L = blockIdx.x;                 // 256 = 8 XCD x 32
  const int w = (L & 7) * 32 + (L >> 3);
  const int bx = w & 7, by = w >> 3;

  __shared__ bf16_t As[128*64];
  __shared__ bf16_t Bs[128*64];

  const int tid = threadIdx.x, lane = tid & 63, wid = tid >> 6;
  const int wm = wid >> 1, wn = wid & 1;
  const int bm0 = by * 128, bn0 = bx * 128;
  const int g = lane >> 4, c = lane & 15;
  const int sr = lane >> 3, sch = lane & 7;

  f32x4 acc[4][4] = {};

  #define STAGEO(kt_)                                                            \
    { _Pragma("unroll")                                                          \
      for (int i = 0; i < 4; ++i) {                                              \
        int r  = wid*32 + i*8 + sr;                                              \
        int ca = sch ^ (r & 7);                                                  \
        load_lds16(A  + (size_t)(bm0 + r)*1024 + (size_t)(kt_)*64 + ca*8,        \
                   &As[(wid*32 + i*8)*64]);                                      \
        load_lds16(Bt + (size_t)(bn0 + r)*1024 + (size_t)(kt_)*64 + ca*8,        \
                   &Bs[(wid*32 + i*8)*64]);                                      \
      } }

  for (int kt = 0; kt < 16; ++kt) {
    STAGEO(kt);
    __syncthreads();
    #pragma unroll
    for (int kk = 0; kk < 2; ++kk) {
      bf16x8 af[4], bfr[4];
      #pragma unroll
      for (int m = 0; m < 4; ++m) {
        int row = wm*64 + m*16 + c;
        int ch  = (kk*4 + g) ^ (row & 7);
        af[m] = *(const bf16x8*)&As[row*64 + ch*8];
      }
      #pragma unroll
      for (int n = 0; n < 4; ++n) {
        int row = wn*64 + n*16 + c;
        int ch  = (kk*4 + g) ^ (row & 7);
        bfr[n] = *(const bf16x8*)&Bs[row*64 + ch*8];
      }
      #pragma unroll
      for (int m = 0; m < 4; ++m)
        #pragma unroll
        for (int n = 0; n < 4; ++n)
          acc[m][n] = __builtin_amdgcn_mfma_f32_16x16x32_bf16(af[m], bfr[n], acc[m][n], 0, 0, 0);
    }
    __syncthreads();
  }
  #undef STAGEO

  #pragma unroll
  for (int n = 0; n < 4; ++n) {
    int col = bn0 + wn*64 + n*16 + c;
    float bn_ = bo[col];
    #pragma unroll
    for (int m = 0; m < 4; ++m) {
      int row0 = bm0 + wm*64 + m*16 + g*4;
      #pragma unroll
      for (int r = 0; r < 4; ++r)
        C[(size_t)(row0 + r)*1024 + col] = acc[m][n][r] + bn_;
    }
  }
}

extern "C" void kernel_launch(void* const* d_in, const int* in_sizes, int n_in,
                              void* d_out, int out_size, void* d_ws, size_t ws_size,
                              hipStream_t stream) {
  const float* iq   = (const float*)d_in[0];
  const float* ikv  = (const float*)d_in[1];
  const float* pq   = (const float*)d_in[2];
  const float* pk   = (const float*)d_in[3];
  const float* pv   = (const float*)d_in[4];
  const float* mask = (const float*)d_in[5];
  const float* wq   = (const float*)d_in[6];
  const float* bq   = (const float*)d_in[7];
  const float* wk   = (const float*)d_in[8];
  const float* bk   = (const float*)d_in[9];
  const float* wv   = (const float*)d_in[10];
  const float* bv   = (const float*)d_in[11];
  const float* wo   = (const float*)d_in[12];
  const float* bo   = (const float*)d_in[13];
  float* out = (float*)d_out;

  char* ws = (char*)d_ws;
  bf16_t* Xq  = (bf16_t*)(ws + (size_t)( 0u<<20));
  bf16_t* Xk  = (bf16_t*)(ws + (size_t)( 8u<<20));
  bf16_t* Xv  = (bf16_t*)(ws + (size_t)(16u<<20));
  bf16_t* Wt  = (bf16_t*)(ws + (size_t)(24u<<20));   // Wqt|Wkt|Wvt contiguous (3072 x 1024)
  bf16_t* Wot = (bf16_t*)(ws + (size_t)(30u<<20));
  bf16_t* Q   = (bf16_t*)(ws + (size_t)(32u<<20));
  bf16_t* K   = (bf16_t*)(ws + (size_t)(40u<<20));
  bf16_t* Vt  = (bf16_t*)(ws + (size_t)(56u<<20));
  bf16_t* X2  = (bf16_t*)(ws + (size_t)(64u<<20));

  k_prep<<<2048, 256, 0, stream>>>(iq, ikv, pq, pk, pv, Xq, Xk, Xv);
  k_wtrans<<<1024, 256, 0, stream>>>(wq, wk, wv, wo, Wt, Wot);
  k_gemm_qkv<<<768, 256, 0, stream>>>(Xq, Xk, Xv, Wt, bq, bk, bv, Q, K, Vt);
  k_attn2<<<512, 512, 0, stream>>>(Q, K, Vt, mask, X2);
  k_gemm_out<<<256, 256, 0, stream>>>(X2, Wot, bo, out);
}

// Round 18
// 109.290 us; speedup vs baseline: 1.2537x; 1.0112x over previous
//
#include <hip/hip_runtime.h>
#include <hip/hip_bf16.h>
#include <stdint.h>

typedef __bf16 bf16_t;
typedef __bf16 bf16x8 __attribute__((ext_vector_type(8)));
typedef __bf16 bf16x4v __attribute__((ext_vector_type(4)));
typedef float  f32x4  __attribute__((ext_vector_type(4)));
typedef float  f32x16 __attribute__((ext_vector_type(16)));
typedef unsigned int u32;
typedef u32 u32x4 __attribute__((ext_vector_type(4)));

#define NEG_BIG (-1e10f)
#define LOG2E 1.44269504f

// async global->LDS, 16B per lane; LDS dest = wave-uniform base + lane*16
__device__ __forceinline__ void load_lds16(const void* gsrc, void* ldst) {
  __builtin_amdgcn_global_load_lds(
      (__attribute__((address_space(1))) void*)(gsrc),
      (__attribute__((address_space(3))) void*)(ldst), 16, 0, 0);
}

__device__ __forceinline__ u32 cvt_pk_bf16(float lo, float hi) {
  u32 r;
  asm("v_cvt_pk_bf16_f32 %0, %1, %2" : "=v"(r) : "v"(lo), "v"(hi));
  return r;
}

// ---------------- 1) merged prep (3-stream blocks) + wtrans ----------------
// Stream-mix fix: each prep block touches ONE X output (2 read streams + 1 write stream,
// long contiguous runs) instead of 8 interleaved streams per wave. ikv is read twice
// (+16 MB) but per-block DRAM page locality recovers copy-class bandwidth.
// blocks 0..2047: Xq=iq+pq | 2048..4095: Xk=ikv+pk | 4096..6143: Xv=ikv+pv | 6144..7167: wtrans
__global__ __launch_bounds__(256) void k_prep_w(
    const float* __restrict__ iq, const float* __restrict__ ikv,
    const float* __restrict__ pq, const float* __restrict__ pk, const float* __restrict__ pv,
    const float* __restrict__ wq, const float* __restrict__ wk,
    const float* __restrict__ wv, const float* __restrict__ wo,
    bf16_t* __restrict__ Xq, bf16_t* __restrict__ Xk, bf16_t* __restrict__ Xv,
    bf16_t* __restrict__ Wt, bf16_t* __restrict__ Wot)
{
  __shared__ float t[64][65];
  int bid = blockIdx.x;
  if (bid < 6144) {
    int z = bid >> 11;                  // 0,1,2
    int i = bid & 2047;
    const float* in = z==0 ? iq : ikv;
    const float* pe = z==0 ? pq : (z==1 ? pk : pv);
    bf16_t*      X  = z==0 ? Xq : (z==1 ? Xk : Xv);
    size_t t0 = (size_t)i * 256 + threadIdx.x;   // 0..524287
    size_t f4 = t0 * 2;
    f32x4 a0 = ((const f32x4*)in)[f4], a1 = ((const f32x4*)in)[f4+1];
    f32x4 p0 = ((const f32x4*)pe)[f4], p1 = ((const f32x4*)pe)[f4+1];
    bf16x8 x;
    #pragma unroll
    for (int e = 0; e < 4; ++e) {
      x[e]     = (bf16_t)(a0[e] + p0[e]);
      x[e + 4] = (bf16_t)(a1[e] + p1[e]);
    }
    *(bf16x8*)&X[t0*8] = x;
  } else {
    int wbid = bid - 6144;              // [0,1024)
    int z = wbid >> 8, rem = wbid & 255;
    const float* src = z==0 ? wq : z==1 ? wk : z==2 ? wv : wo;
    bf16_t*      dst = z < 3 ? (Wt + (size_t)z*(1u<<20)) : Wot;
    int n0 = (rem & 15) << 6, k0 = (rem >> 4) << 6;
    int c = threadIdx.x & 63, rb = threadIdx.x >> 6;
    #pragma unroll
    for (int i = 0; i < 16; ++i) {
      int r = i*4 + rb;
      t[r][c] = src[(size_t)(k0 + r)*1024 + n0 + c];
    }
    __syncthreads();
    int n = threadIdx.x & 63, hq = threadIdx.x >> 6;
    #pragma unroll
    for (int j = 0; j < 2; ++j) {
      int kk = hq*2 + j;                // 8-col chunk index
      bf16x8 vv;
      #pragma unroll
      for (int e = 0; e < 8; ++e) vv[e] = (bf16_t)t[kk*8 + e][n];
      *(bf16x8*)&dst[(size_t)(n0 + n)*1024 + k0 + kk*8] = vv;
    }
  }
}

// ---------------- 3) QKV GEMM: C(4096 x 3072) = A_z * Wt^T; 128x128, BK=64 (R6/R14 proven form) ----------------
// Q is pre-scaled by (1/8)*log2e so the attention softmax can run in exp2 domain.
__global__ __launch_bounds__(256, 3) void k_gemm_qkv(
    const bf16_t* __restrict__ Xq, const bf16_t* __restrict__ Xk, const bf16_t* __restrict__ Xv,
    const bf16_t* __restrict__ Wt,
    const float* __restrict__ bq, const float* __restrict__ bk, const float* __restrict__ bv,
    bf16_t* __restrict__ Qo, bf16_t* __restrict__ Ko, bf16_t* __restrict__ Vt)
{
  const int L = blockIdx.x;                         // 768 = 8 XCD x 96
  const int w = (L & 7) * 96 + (L >> 3);
  const int bx = w & 7, by = (w >> 3) & 31, bz = w >> 8;
  const int bn = bz * 8 + bx;

  const bf16_t* A = bz==0 ? Xq : bz==1 ? Xk : Xv;
  const float* bias = bz==0 ? bq : bz==1 ? bk : bv;

  __shared__ bf16_t As[128*64];
  __shared__ bf16_t Bs[128*64];

  const int tid = threadIdx.x, lane = tid & 63, wid = tid >> 6;
  const int wm = wid >> 1, wn = wid & 1;
  const int bm0 = by * 128;
  const int bn0g = bn * 128;                        // row of Wt (0..3071)
  const int g = lane >> 4, c = lane & 15;
  const int sr = lane >> 3, sch = lane & 7;

  f32x4 acc[4][4] = {};

  #define STAGE(kt_)                                                             \
    { _Pragma("unroll")                                                          \
      for (int i = 0; i < 4; ++i) {                                              \
        int r  = wid*32 + i*8 + sr;                                              \
        int ca = sch ^ (r & 7);                                                  \
        load_lds16(A  + (size_t)(bm0  + r)*1024 + (size_t)(kt_)*64 + ca*8,       \
                   &As[(wid*32 + i*8)*64]);                                      \
        load_lds16(Wt + (size_t)(bn0g + r)*1024 + (size_t)(kt_)*64 + ca*8,       \
                   &Bs[(wid*32 + i*8)*64]);                                      \
      } }

  for (int kt = 0; kt < 16; ++kt) {
    STAGE(kt);
    __syncthreads();
    #pragma unroll
    for (int kk = 0; kk < 2; ++kk) {
      bf16x8 af[4], bfr[4];
      #pragma unroll
      for (int m = 0; m < 4; ++m) {
        int row = wm*64 + m*16 + c;
        int ch  = (kk*4 + g) ^ (row & 7);
        af[m] = *(const bf16x8*)&As[row*64 + ch*8];
      }
      #pragma unroll
      for (int n = 0; n < 4; ++n) {
        int row = wn*64 + n*16 + c;
        int ch  = (kk*4 + g) ^ (row & 7);
        bfr[n] = *(const bf16x8*)&Bs[row*64 + ch*8];
      }
      #pragma unroll
      for (int m = 0; m < 4; ++m)
        #pragma unroll
        for (int n = 0; n < 4; ++n)
          acc[m][n] = __builtin_amdgcn_mfma_f32_16x16x32_bf16(af[m], bfr[n], acc[m][n], 0, 0, 0);
    }
    __syncthreads();
  }
  #undef STAGE

  if (bz < 2) {
    bf16_t* C = bz==0 ? Qo : Ko;
    const float scale = bz==0 ? 0.125f * LOG2E : 1.0f;
    #pragma unroll
    for (int n = 0; n < 4; ++n) {
      int col = (bn0g & 1023) + wn*64 + n*16 + c;
      float bn_ = bias[col];
      #pragma unroll
      for (int m = 0; m < 4; ++m) {
        int row0 = bm0 + wm*64 + m*16 + g*4;
        #pragma unroll
        for (int r = 0; r < 4; ++r)
          C[(size_t)(row0 + r)*1024 + col] = (bf16_t)((acc[m][n][r] + bn_) * scale);
      }
    }
  } else {
    // V panel: write transposed into Vt[(b*16+h)*64+hd][s]
    #pragma unroll
    for (int n = 0; n < 4; ++n) {
      int colz = (bn0g & 1023) + wn*64 + n*16 + c;  // h*64+hd
      float bn_ = bias[colz];
      int h = colz >> 6, hd = colz & 63;
      #pragma unroll
      for (int m = 0; m < 4; ++m) {
        int row0 = bm0 + wm*64 + m*16 + g*4;        // b*1024 + s0
        int b = row0 >> 10, s0 = row0 & 1023;
        bf16x4v v4;
        #pragma unroll
        for (int r = 0; r < 4; ++r) v4[r] = (bf16_t)(acc[m][n][r] + bn_);
        *(bf16x4v*)&Vt[(size_t)((b*16 + h)*64 + hd)*1024 + s0] = v4;
      }
    }
  }
}

// ---------------- 5) flash attention, swapped-QK^T, no-max exp2 softmax, SPLIT-KV x2 ----------------
__global__ __launch_bounds__(512, 4) void k_attn2(
    const bf16_t* __restrict__ Qm, const bf16_t* __restrict__ Km,
    const bf16_t* __restrict__ Vt, const float* __restrict__ mask,
    bf16_t* __restrict__ X2)
{
  __shared__ bf16_t Ks[2][2][64*64];  // [half][buf][kv][hd], chunk-swizzled
  __shared__ bf16_t Vs[2][2][64*64];  // [half][buf][hd][kv] (aliased as obuf in epilogue)
  __shared__ float  bias_lds[1024];   // (1-mask)*NEG_BIG*log2e for this batch
  __shared__ int    tflag[16];        // per-kv-tile "has any masked key" flag
  __shared__ float  l_lds[4][32];     // half-0 total l
  __shared__ float  l2_lds[4][32];    // half-1 partial l

  const int L = blockIdx.x;           // 512 = 8 XCD x 64
  const int kk_ = L >> 3;
  const int bh = (L & 7) * 8 + (kk_ >> 3);
  const int qt = kk_ & 7;
  const int b = bh >> 4, h = bh & 15;

  const int tid = threadIdx.x, lane = tid & 63, wid = tid >> 6;  // wid 0..7
  const int half = wid >> 2, w4 = wid & 3;
  const int lq = lane & 31;           // q column
  const int hi = lane >> 5;

  if (tid < 16) tflag[tid] = 0;
  __syncthreads();
  {
    float2 m2 = *(const float2*)&mask[b*1024 + tid*2];
    float2 b2;
    b2.x = (1.0f - m2.x) * (NEG_BIG * LOG2E);
    b2.y = (1.0f - m2.y) * (NEG_BIG * LOG2E);
    *(float2*)&bias_lds[tid*2] = b2;
    if (b2.x != 0.f || b2.y != 0.f)
      tflag[tid >> 5] = 1;            // tile kt covers mask idx [kt*64, kt*64+64)
  }

  const int q0w = qt*128 + w4*32;
  bf16x8 qf[4];
  #pragma unroll
  for (int kb = 0; kb < 4; ++kb)
    qf[kb] = *(const bf16x8*)&Qm[(size_t)(b*1024 + q0w + lq)*1024 + h*64 + kb*16 + hi*8];

  f32x16 oacc[2] = {};
  float lsum = 0.f;

  const int sr8 = (lane >> 3);
  const int sc8 = lane & 7;
  #define STAGE(bufi, kv0)                                                        \
    {                                                                             \
      _Pragma("unroll")                                                           \
      for (int cc = 0; cc < 2; ++cc) {                                            \
        int r  = cc*32 + w4*8 + sr8;                                              \
        int ca = sc8 ^ (r & 7);                                                   \
        load_lds16(Km + (size_t)(b*1024 + (kv0) + r)*1024 + h*64 + ca*8,          \
                   &Ks[half][bufi][(cc*32 + w4*8)*64]);                           \
        load_lds16(Vt + (size_t)((b*16 + h)*64 + r)*1024 + (kv0) + ca*8,          \
                   &Vs[half][bufi][(cc*32 + w4*8)*64]);                           \
      }                                                                           \
    }

  STAGE(0, half*512);
  __syncthreads();                    // publishes stage 0 (both halves), bias_lds, tflag

  for (int t = 0; t < 8; ++t) {
    const int kt = half*8 + t;
    const int buf = t & 1;
    if (t < 7) STAGE(buf ^ 1, (kt + 1) * 64);

    f32x16 s[2];
    __builtin_amdgcn_s_setprio(1);
    #pragma unroll
    for (int blk = 0; blk < 2; ++blk) {
      f32x16 acc = {};
      #pragma unroll
      for (int kb = 0; kb < 4; ++kb) {
        int row = blk*32 + lq;
        int ch  = (kb*2 + hi) ^ (row & 7);
        bf16x8 kf = *(const bf16x8*)&Ks[half][buf][row*64 + ch*8];
        acc = __builtin_amdgcn_mfma_f32_32x32x16_bf16(kf, qf[kb], acc, 0, 0, 0);
      }
      s[blk] = acc;
    }
    __builtin_amdgcn_s_setprio(0);

    if (tflag[kt]) {                  // wave-uniform; skipped when tile has no masked keys
      #pragma unroll
      for (int blk = 0; blk < 2; ++blk)
        #pragma unroll
        for (int g2 = 0; g2 < 4; ++g2) {
          float4 b4 = *(const float4*)&bias_lds[kt*64 + blk*32 + g2*8 + hi*4];
          s[blk][g2*4+0] += b4.x;
          s[blk][g2*4+1] += b4.y;
          s[blk][g2*4+2] += b4.z;
          s[blk][g2*4+3] += b4.w;
        }
    }

    // no-max softmax: P = exp2(min(s, 60)); masked -> exp2(-1.4e10) = 0 exactly.
    #pragma unroll
    for (int blk = 0; blk < 2; ++blk)
      #pragma unroll
      for (int r = 0; r < 16; ++r) {
        float sv = fminf(s[blk][r], 60.0f);
        asm("v_exp_f32 %0, %1" : "=v"(sv) : "v"(sv));
        s[blk][r] = sv;
      }

    // pairwise tree-sum of the 32 P values (depth 5)
    float ts[8];
    #pragma unroll
    for (int r = 0; r < 8; ++r)
      ts[r] = (s[0][r] + s[0][r+8]) + (s[1][r] + s[1][r+8]);
    float s0 = (ts[0] + ts[1]) + (ts[2] + ts[3]);
    float s1 = (ts[4] + ts[5]) + (ts[6] + ts[7]);
    float rsum = s0 + s1;
    lsum += rsum + __shfl_xor(rsum, 32, 64);

    // P -> bf16 A-fragments in-register (T12)
    u32 paw[4][4];
    #pragma unroll
    for (int blk = 0; blk < 2; ++blk)
      #pragma unroll
      for (int hf = 0; hf < 2; ++hf) {
        int base = hf * 8;
        #pragma unroll
        for (int w2 = 0; w2 < 2; ++w2) {
          u32 x = cvt_pk_bf16(s[blk][base + 2*w2],     s[blk][base + 2*w2 + 1]);
          u32 y = cvt_pk_bf16(s[blk][base + 4 + 2*w2], s[blk][base + 4 + 2*w2 + 1]);
          asm("v_permlane32_swap_b32 %0, %1" : "+v"(x), "+v"(y));
          paw[blk*2 + hf][w2]     = x;
          paw[blk*2 + hf][w2 + 2] = y;
        }
      }

    __builtin_amdgcn_s_setprio(1);
    #pragma unroll
    for (int ks = 0; ks < 4; ++ks) {
      u32x4 t2 = { paw[ks][0], paw[ks][1], paw[ks][2], paw[ks][3] };
      bf16x8 pa = __builtin_bit_cast(bf16x8, t2);
      #pragma unroll
      for (int nb = 0; nb < 2; ++nb) {
        int row = nb*32 + lq;
        int ch  = (ks*2 + hi) ^ (row & 7);
        bf16x8 vf = *(const bf16x8*)&Vs[half][buf][row*64 + ch*8];
        oacc[nb] = __builtin_amdgcn_mfma_f32_32x32x16_bf16(pa, vf, oacc[nb], 0, 0, 0);
      }
    }
    __builtin_amdgcn_s_setprio(0);
    __syncthreads();
  }
  #undef STAGE

  // ---- combine halves: l = l0+l1, O = O0+O1 (un-normalized partials share scale) ----
  float* obuf = (float*)&Vs[0][0][0];   // 32 KB, Vs is dead now
  // obuf layout: [w4][hi][reg(16)][nb(2)][lq(32)]
  if (half == 1) {
    l2_lds[w4][lq] = lsum;              // lanes hi=0/1 write same value (both hold l[q=lq])
    #pragma unroll
    for (int nb = 0; nb < 2; ++nb)
      #pragma unroll
      for (int reg = 0; reg < 16; ++reg)
        obuf[((((w4*2 + hi)*16 + reg)*2) + nb)*32 + lq] = oacc[nb][reg];
  }
  __syncthreads();
  if (half == 0) {
    float lt = lsum + l2_lds[w4][lq];
    l_lds[w4][lq] = lt;
  }
  __syncthreads();
  if (half == 0) {
    #pragma unroll
    for (int g2 = 0; g2 < 4; ++g2)
      #pragma unroll
      for (int j = 0; j < 4; ++j) {
        int reg  = g2*4 + j;
        int qrow = j + 8*g2 + 4*hi;
        float inv = 1.0f / l_lds[w4][qrow];
        #pragma unroll
        for (int nb = 0; nb < 2; ++nb) {
          float o = oacc[nb][reg] + obuf[((((w4*2 + hi)*16 + reg)*2) + nb)*32 + lq];
          X2[(size_t)(b*1024 + q0w + qrow)*1024 + h*64 + nb*32 + lq] = (bf16_t)(o * inv);
        }
      }
  }
}

// ---------------- 6) output GEMM: out = X2 * Wot^T + bo (fp32), single-buffered ----------------
__global__ __launch_bounds__(256, 3) void k_gemm_out(
    const bf16_t* __restrict__ A, const bf16_t* __restrict__ Bt,
    const float* __restrict__ bo, float* __restrict__ C)
{
  const int L = blockIdx.x;                 // 256 = 8 XCD x 32
  const int w = (L & 7) * 32 + (L >> 3);
  const int bx = w & 7, by = w >> 3;

  __shared__ bf16_t As[128*64];
  __shared__ bf16_t Bs[128*64];

  const int tid = threadIdx.x, lane = tid & 63, wid = tid >> 6;
  const int wm = wid >> 1, wn = wid & 1;
  const int bm0 = by * 128, bn0 = bx * 128;
  const int g = lane >> 4, c = lane & 15;
  const int sr = lane >> 3, sch = lane & 7;

  f32x4 acc[4][4] = {};

  #define STAGEO(kt_)                                                            \
    { _Pragma("unroll")                                                          \
      for (int i = 0; i < 4; ++i) {                                              \
        int r  = wid*32 + i*8 + sr;                                              \
        int ca = sch ^ (r & 7);                                                  \
        load_lds16(A  + (size_t)(bm0 + r)*1024 + (size_t)(kt_)*64 + ca*8,        \
                   &As[(wid*32 + i*8)*64]);                                      \
        load_lds16(Bt + (size_t)(bn0 + r)*1024 + (size_t)(kt_)*64 + ca*8,        \
                   &Bs[(wid*32 + i*8)*64]);                                      \
      } }

  for (int kt = 0; kt < 16; ++kt) {
    STAGEO(kt);
    __syncthreads();
    #pragma unroll
    for (int kk = 0; kk < 2; ++kk) {
      bf16x8 af[4], bfr[4];
      #pragma unroll
      for (int m = 0; m < 4; ++m) {
        int row = wm*64 + m*16 + c;
        int ch  = (kk*4 + g) ^ (row & 7);
        af[m] = *(const bf16x8*)&As[row*64 + ch*8];
      }
      #pragma unroll
      for (int n = 0; n < 4; ++n) {
        int row = wn*64 + n*16 + c;
        int ch  = (kk*4 + g) ^ (row & 7);
        bfr[n] = *(const bf16x8*)&Bs[row*64 + ch*8];
      }
      #pragma unroll
      for (int m = 0; m < 4; ++m)
        #pragma unroll
        for (int n = 0; n < 4; ++n)
          acc[m][n] = __builtin_amdgcn_mfma_f32_16x16x32_bf16(af[m], bfr[n], acc[m][n], 0, 0, 0);
    }
    __syncthreads();
  }
  #undef STAGEO

  #pragma unroll
  for (int n = 0; n < 4; ++n) {
    int col = bn0 + wn*64 + n*16 + c;
    float bn_ = bo[col];
    #pragma unroll
    for (int m = 0; m < 4; ++m) {
      int row0 = bm0 + wm*64 + m*16 + g*4;
      #pragma unroll
      for (int r = 0; r < 4; ++r)
        C[(size_t)(row0 + r)*1024 + col] = acc[m][n][r] + bn_;
    }
  }
}

extern "C" void kernel_launch(void* const* d_in, const int* in_sizes, int n_in,
                              void* d_out, int out_size, void* d_ws, size_t ws_size,
                              hipStream_t stream) {
  const float* iq   = (const float*)d_in[0];
  const float* ikv  = (const float*)d_in[1];
  const float* pq   = (const float*)d_in[2];
  const float* pk   = (const float*)d_in[3];
  const float* pv   = (const float*)d_in[4];
  const float* mask = (const float*)d_in[5];
  const float* wq   = (const float*)d_in[6];
  const float* bq   = (const float*)d_in[7];
  const float* wk   = (const float*)d_in[8];
  const float* bk   = (const float*)d_in[9];
  const float* wv   = (const float*)d_in[10];
  const float* bv   = (const float*)d_in[11];
  const float* wo   = (const float*)d_in[12];
  const float* bo   = (const float*)d_in[13];
  float* out = (float*)d_out;

  char* ws = (char*)d_ws;
  bf16_t* Xq  = (bf16_t*)(ws + (size_t)( 0u<<20));
  bf16_t* Xk  = (bf16_t*)(ws + (size_t)( 8u<<20));
  bf16_t* Xv  = (bf16_t*)(ws + (size_t)(16u<<20));
  bf16_t* Wt  = (bf16_t*)(ws + (size_t)(24u<<20));   // Wqt|Wkt|Wvt contiguous (3072 x 1024)
  bf16_t* Wot = (bf16_t*)(ws + (size_t)(30u<<20));
  bf16_t* Q   = (bf16_t*)(ws + (size_t)(32u<<20));
  bf16_t* K   = (bf16_t*)(ws + (size_t)(40u<<20));
  bf16_t* Vt  = (bf16_t*)(ws + (size_t)(56u<<20));
  bf16_t* X2  = (bf16_t*)(ws + (size_t)(64u<<20));

  k_prep_w<<<7168, 256, 0, stream>>>(iq, ikv, pq, pk, pv, wq, wk, wv, wo,
                                     Xq, Xk, Xv, Wt, Wot);
  k_gemm_qkv<<<768, 256, 0, stream>>>(Xq, Xk, Xv, Wt, bq, bk, bv, Q, K, Vt);
  k_attn2<<<512, 512, 0, stream>>>(Q, K, Vt, mask, X2);
  k_gemm_out<<<256, 256, 0, stream>>>(X2, Wot, bo, out);
}

// Round 19
// 107.802 us; speedup vs baseline: 1.2710x; 1.0138x over previous
//
#include <hip/hip_runtime.h>
#include <hip/hip_bf16.h>
#include <stdint.h>

typedef __bf16 bf16_t;
typedef __bf16 bf16x8 __attribute__((ext_vector_type(8)));
typedef __bf16 bf16x4v __attribute__((ext_vector_type(4)));
typedef float  f32x4  __attribute__((ext_vector_type(4)));
typedef float  f32x16 __attribute__((ext_vector_type(16)));
typedef unsigned int u32;
typedef u32 u32x4 __attribute__((ext_vector_type(4)));

#define NEG_BIG (-1e10f)
#define LOG2E 1.44269504f

// async global->LDS, 16B per lane; LDS dest = wave-uniform base + lane*16
__device__ __forceinline__ void load_lds16(const void* gsrc, void* ldst) {
  __builtin_amdgcn_global_load_lds(
      (__attribute__((address_space(1))) void*)(gsrc),
      (__attribute__((address_space(3))) void*)(ldst), 16, 0, 0);
}

__device__ __forceinline__ u32 cvt_pk_bf16(float lo, float hi) {
  u32 r;
  asm("v_cvt_pk_bf16_f32 %0, %1, %2" : "=v"(r) : "v"(lo), "v"(hi));
  return r;
}

// ---------------- 1) merged prep (R14 best-measured form): add+cast 8/thread | wtrans 16B-store ----------------
__global__ __launch_bounds__(256) void k_prep_w(
    const float* __restrict__ iq, const float* __restrict__ ikv,
    const float* __restrict__ pq, const float* __restrict__ pk, const float* __restrict__ pv,
    const float* __restrict__ wq, const float* __restrict__ wk,
    const float* __restrict__ wv, const float* __restrict__ wo,
    bf16_t* __restrict__ Xq, bf16_t* __restrict__ Xk, bf16_t* __restrict__ Xv,
    bf16_t* __restrict__ Wt, bf16_t* __restrict__ Wot)
{
  __shared__ float t[64][65];
  if (blockIdx.x < 2048) {
    // add + cast, 8 fp32 per thread, 16B bf16x8 stores
    size_t t0 = (size_t)blockIdx.x * 256 + threadIdx.x;   // 0..524287
    size_t f4 = t0 * 2;
    f32x4 a0  = ((const f32x4*)iq)[f4],  a1  = ((const f32x4*)iq)[f4+1];
    f32x4 b0  = ((const f32x4*)ikv)[f4], b1  = ((const f32x4*)ikv)[f4+1];
    f32x4 eq0 = ((const f32x4*)pq)[f4],  eq1 = ((const f32x4*)pq)[f4+1];
    f32x4 ek0 = ((const f32x4*)pk)[f4],  ek1 = ((const f32x4*)pk)[f4+1];
    f32x4 ev0 = ((const f32x4*)pv)[f4],  ev1 = ((const f32x4*)pv)[f4+1];
    bf16x8 q, k, v;
    #pragma unroll
    for (int e = 0; e < 4; ++e) {
      q[e] = (bf16_t)(a0[e] + eq0[e]); q[e+4] = (bf16_t)(a1[e] + eq1[e]);
      k[e] = (bf16_t)(b0[e] + ek0[e]); k[e+4] = (bf16_t)(b1[e] + ek1[e]);
      v[e] = (bf16_t)(b0[e] + ev0[e]); v[e+4] = (bf16_t)(b1[e] + ev1[e]);
    }
    *(bf16x8*)&Xq[t0*8] = q;
    *(bf16x8*)&Xk[t0*8] = k;
    *(bf16x8*)&Xv[t0*8] = v;
  } else {
    int bid = blockIdx.x - 2048;          // [0,1024)
    int z = bid >> 8, rem = bid & 255;
    const float* src = z==0 ? wq : z==1 ? wk : z==2 ? wv : wo;
    bf16_t*      dst = z < 3 ? (Wt + (size_t)z*(1u<<20)) : Wot;
    int n0 = (rem & 15) << 6, k0 = (rem >> 4) << 6;
    int c = threadIdx.x & 63, rb = threadIdx.x >> 6;
    #pragma unroll
    for (int i = 0; i < 16; ++i) {
      int r = i*4 + rb;
      t[r][c] = src[(size_t)(k0 + r)*1024 + n0 + c];
    }
    __syncthreads();
    int n = threadIdx.x & 63, hq = threadIdx.x >> 6;
    #pragma unroll
    for (int j = 0; j < 2; ++j) {
      int kk = hq*2 + j;                  // 8-col chunk index
      bf16x8 vv;
      #pragma unroll
      for (int e = 0; e < 8; ++e) vv[e] = (bf16_t)t[kk*8 + e][n];
      *(bf16x8*)&dst[(size_t)(n0 + n)*1024 + k0 + kk*8] = vv;
    }
  }
}

// ---------------- 3) QKV GEMM: C(4096 x 3072) = A_z * Wt^T; 128x128, BK=64 (R6/R14 proven form) ----------------
// Q is pre-scaled by (1/8)*log2e so the attention softmax can run in exp2 domain.
__global__ __launch_bounds__(256, 3) void k_gemm_qkv(
    const bf16_t* __restrict__ Xq, const bf16_t* __restrict__ Xk, const bf16_t* __restrict__ Xv,
    const bf16_t* __restrict__ Wt,
    const float* __restrict__ bq, const float* __restrict__ bk, const float* __restrict__ bv,
    bf16_t* __restrict__ Qo, bf16_t* __restrict__ Ko, bf16_t* __restrict__ Vt)
{
  const int L = blockIdx.x;                         // 768 = 8 XCD x 96
  const int w = (L & 7) * 96 + (L >> 3);
  const int bx = w & 7, by = (w >> 3) & 31, bz = w >> 8;
  const int bn = bz * 8 + bx;

  const bf16_t* A = bz==0 ? Xq : bz==1 ? Xk : Xv;
  const float* bias = bz==0 ? bq : bz==1 ? bk : bv;

  __shared__ bf16_t As[128*64];
  __shared__ bf16_t Bs[128*64];

  const int tid = threadIdx.x, lane = tid & 63, wid = tid >> 6;
  const int wm = wid >> 1, wn = wid & 1;
  const int bm0 = by * 128;
  const int bn0g = bn * 128;                        // row of Wt (0..3071)
  const int g = lane >> 4, c = lane & 15;
  const int sr = lane >> 3, sch = lane & 7;

  f32x4 acc[4][4] = {};

  #define STAGE(kt_)                                                             \
    { _Pragma("unroll")                                                          \
      for (int i = 0; i < 4; ++i) {                                              \
        int r  = wid*32 + i*8 + sr;                                              \
        int ca = sch ^ (r & 7);                                                  \
        load_lds16(A  + (size_t)(bm0  + r)*1024 + (size_t)(kt_)*64 + ca*8,       \
                   &As[(wid*32 + i*8)*64]);                                      \
        load_lds16(Wt + (size_t)(bn0g + r)*1024 + (size_t)(kt_)*64 + ca*8,       \
                   &Bs[(wid*32 + i*8)*64]);                                      \
      } }

  for (int kt = 0; kt < 16; ++kt) {
    STAGE(kt);
    __syncthreads();
    #pragma unroll
    for (int kk = 0; kk < 2; ++kk) {
      bf16x8 af[4], bfr[4];
      #pragma unroll
      for (int m = 0; m < 4; ++m) {
        int row = wm*64 + m*16 + c;
        int ch  = (kk*4 + g) ^ (row & 7);
        af[m] = *(const bf16x8*)&As[row*64 + ch*8];
      }
      #pragma unroll
      for (int n = 0; n < 4; ++n) {
        int row = wn*64 + n*16 + c;
        int ch  = (kk*4 + g) ^ (row & 7);
        bfr[n] = *(const bf16x8*)&Bs[row*64 + ch*8];
      }
      #pragma unroll
      for (int m = 0; m < 4; ++m)
        #pragma unroll
        for (int n = 0; n < 4; ++n)
          acc[m][n] = __builtin_amdgcn_mfma_f32_16x16x32_bf16(af[m], bfr[n], acc[m][n], 0, 0, 0);
    }
    __syncthreads();
  }
  #undef STAGE

  if (bz < 2) {
    bf16_t* C = bz==0 ? Qo : Ko;
    const float scale = bz==0 ? 0.125f * LOG2E : 1.0f;
    #pragma unroll
    for (int n = 0; n < 4; ++n) {
      int col = (bn0g & 1023) + wn*64 + n*16 + c;
      float bn_ = bias[col];
      #pragma unroll
      for (int m = 0; m < 4; ++m) {
        int row0 = bm0 + wm*64 + m*16 + g*4;
        #pragma unroll
        for (int r = 0; r < 4; ++r)
          C[(size_t)(row0 + r)*1024 + col] = (bf16_t)((acc[m][n][r] + bn_) * scale);
      }
    }
  } else {
    // V panel: write transposed into Vt[(b*16+h)*64+hd][s]
    #pragma unroll
    for (int n = 0; n < 4; ++n) {
      int colz = (bn0g & 1023) + wn*64 + n*16 + c;  // h*64+hd
      float bn_ = bias[colz];
      int h = colz >> 6, hd = colz & 63;
      #pragma unroll
      for (int m = 0; m < 4; ++m) {
        int row0 = bm0 + wm*64 + m*16 + g*4;        // b*1024 + s0
        int b = row0 >> 10, s0 = row0 & 1023;
        bf16x4v v4;
        #pragma unroll
        for (int r = 0; r < 4; ++r) v4[r] = (bf16_t)(acc[m][n][r] + bn_);
        *(bf16x4v*)&Vt[(size_t)((b*16 + h)*64 + hd)*1024 + s0] = v4;
      }
    }
  }
}

// ---------------- 5) flash attention, swapped-QK^T, no-max exp2 softmax, SPLIT-KV x2 ----------------
__global__ __launch_bounds__(512, 4) void k_attn2(
    const bf16_t* __restrict__ Qm, const bf16_t* __restrict__ Km,
    const bf16_t* __restrict__ Vt, const float* __restrict__ mask,
    bf16_t* __restrict__ X2)
{
  __shared__ bf16_t Ks[2][2][64*64];  // [half][buf][kv][hd], chunk-swizzled
  __shared__ bf16_t Vs[2][2][64*64];  // [half][buf][hd][kv] (aliased as obuf in epilogue)
  __shared__ float  bias_lds[1024];   // (1-mask)*NEG_BIG*log2e for this batch
  __shared__ int    tflag[16];        // per-kv-tile "has any masked key" flag
  __shared__ float  l_lds[4][32];     // half-0 total l
  __shared__ float  l2_lds[4][32];    // half-1 partial l

  const int L = blockIdx.x;           // 512 = 8 XCD x 64
  const int kk_ = L >> 3;
  const int bh = (L & 7) * 8 + (kk_ >> 3);
  const int qt = kk_ & 7;
  const int b = bh >> 4, h = bh & 15;

  const int tid = threadIdx.x, lane = tid & 63, wid = tid >> 6;  // wid 0..7
  const int half = wid >> 2, w4 = wid & 3;
  const int lq = lane & 31;           // q column
  const int hi = lane >> 5;

  if (tid < 16) tflag[tid] = 0;
  __syncthreads();
  {
    float2 m2 = *(const float2*)&mask[b*1024 + tid*2];
    float2 b2;
    b2.x = (1.0f - m2.x) * (NEG_BIG * LOG2E);
    b2.y = (1.0f - m2.y) * (NEG_BIG * LOG2E);
    *(float2*)&bias_lds[tid*2] = b2;
    if (b2.x != 0.f || b2.y != 0.f)
      tflag[tid >> 5] = 1;            // tile kt covers mask idx [kt*64, kt*64+64)
  }

  const int q0w = qt*128 + w4*32;
  bf16x8 qf[4];
  #pragma unroll
  for (int kb = 0; kb < 4; ++kb)
    qf[kb] = *(const bf16x8*)&Qm[(size_t)(b*1024 + q0w + lq)*1024 + h*64 + kb*16 + hi*8];

  f32x16 oacc[2] = {};
  float lsum = 0.f;

  const int sr8 = (lane >> 3);
  const int sc8 = lane & 7;
  #define STAGE(bufi, kv0)                                                        \
    {                                                                             \
      _Pragma("unroll")                                                           \
      for (int cc = 0; cc < 2; ++cc) {                                            \
        int r  = cc*32 + w4*8 + sr8;                                              \
        int ca = sc8 ^ (r & 7);                                                   \
        load_lds16(Km + (size_t)(b*1024 + (kv0) + r)*1024 + h*64 + ca*8,          \
                   &Ks[half][bufi][(cc*32 + w4*8)*64]);                           \
        load_lds16(Vt + (size_t)((b*16 + h)*64 + r)*1024 + (kv0) + ca*8,          \
                   &Vs[half][bufi][(cc*32 + w4*8)*64]);                           \
      }                                                                           \
    }

  STAGE(0, half*512);
  __syncthreads();                    // publishes stage 0 (both halves), bias_lds, tflag

  for (int t = 0; t < 8; ++t) {
    const int kt = half*8 + t;
    const int buf = t & 1;
    if (t < 7) STAGE(buf ^ 1, (kt + 1) * 64);

    f32x16 s[2];
    __builtin_amdgcn_s_setprio(1);
    #pragma unroll
    for (int blk = 0; blk < 2; ++blk) {
      f32x16 acc = {};
      #pragma unroll
      for (int kb = 0; kb < 4; ++kb) {
        int row = blk*32 + lq;
        int ch  = (kb*2 + hi) ^ (row & 7);
        bf16x8 kf = *(const bf16x8*)&Ks[half][buf][row*64 + ch*8];
        acc = __builtin_amdgcn_mfma_f32_32x32x16_bf16(kf, qf[kb], acc, 0, 0, 0);
      }
      s[blk] = acc;
    }
    __builtin_amdgcn_s_setprio(0);

    if (tflag[kt]) {                  // wave-uniform; skipped when tile has no masked keys
      #pragma unroll
      for (int blk = 0; blk < 2; ++blk)
        #pragma unroll
        for (int g2 = 0; g2 < 4; ++g2) {
          float4 b4 = *(const float4*)&bias_lds[kt*64 + blk*32 + g2*8 + hi*4];
          s[blk][g2*4+0] += b4.x;
          s[blk][g2*4+1] += b4.y;
          s[blk][g2*4+2] += b4.z;
          s[blk][g2*4+3] += b4.w;
        }
    }

    // no-max softmax: P = exp2(min(s, 60)); masked -> exp2(-1.4e10) = 0 exactly.
    #pragma unroll
    for (int blk = 0; blk < 2; ++blk)
      #pragma unroll
      for (int r = 0; r < 16; ++r) {
        float sv = fminf(s[blk][r], 60.0f);
        asm("v_exp_f32 %0, %1" : "=v"(sv) : "v"(sv));
        s[blk][r] = sv;
      }

    // pairwise tree-sum of the 32 P values (depth 5)
    float ts[8];
    #pragma unroll
    for (int r = 0; r < 8; ++r)
      ts[r] = (s[0][r] + s[0][r+8]) + (s[1][r] + s[1][r+8]);
    float s0 = (ts[0] + ts[1]) + (ts[2] + ts[3]);
    float s1 = (ts[4] + ts[5]) + (ts[6] + ts[7]);
    float rsum = s0 + s1;
    lsum += rsum + __shfl_xor(rsum, 32, 64);

    // P -> bf16 A-fragments in-register (T12)
    u32 paw[4][4];
    #pragma unroll
    for (int blk = 0; blk < 2; ++blk)
      #pragma unroll
      for (int hf = 0; hf < 2; ++hf) {
        int base = hf * 8;
        #pragma unroll
        for (int w2 = 0; w2 < 2; ++w2) {
          u32 x = cvt_pk_bf16(s[blk][base + 2*w2],     s[blk][base + 2*w2 + 1]);
          u32 y = cvt_pk_bf16(s[blk][base + 4 + 2*w2], s[blk][base + 4 + 2*w2 + 1]);
          asm("v_permlane32_swap_b32 %0, %1" : "+v"(x), "+v"(y));
          paw[blk*2 + hf][w2]     = x;
          paw[blk*2 + hf][w2 + 2] = y;
        }
      }

    __builtin_amdgcn_s_setprio(1);
    #pragma unroll
    for (int ks = 0; ks < 4; ++ks) {
      u32x4 t2 = { paw[ks][0], paw[ks][1], paw[ks][2], paw[ks][3] };
      bf16x8 pa = __builtin_bit_cast(bf16x8, t2);
      #pragma unroll
      for (int nb = 0; nb < 2; ++nb) {
        int row = nb*32 + lq;
        int ch  = (ks*2 + hi) ^ (row & 7);
        bf16x8 vf = *(const bf16x8*)&Vs[half][buf][row*64 + ch*8];
        oacc[nb] = __builtin_amdgcn_mfma_f32_32x32x16_bf16(pa, vf, oacc[nb], 0, 0, 0);
      }
    }
    __builtin_amdgcn_s_setprio(0);
    __syncthreads();
  }
  #undef STAGE

  // ---- combine halves: l = l0+l1, O = O0+O1 (un-normalized partials share scale) ----
  float* obuf = (float*)&Vs[0][0][0];   // 32 KB, Vs is dead now
  // obuf layout: [w4][hi][reg(16)][nb(2)][lq(32)]
  if (half == 1) {
    l2_lds[w4][lq] = lsum;              // lanes hi=0/1 write same value (both hold l[q=lq])
    #pragma unroll
    for (int nb = 0; nb < 2; ++nb)
      #pragma unroll
      for (int reg = 0; reg < 16; ++reg)
        obuf[((((w4*2 + hi)*16 + reg)*2) + nb)*32 + lq] = oacc[nb][reg];
  }
  __syncthreads();
  if (half == 0) {
    float lt = lsum + l2_lds[w4][lq];
    l_lds[w4][lq] = lt;
  }
  __syncthreads();
  if (half == 0) {
    #pragma unroll
    for (int g2 = 0; g2 < 4; ++g2)
      #pragma unroll
      for (int j = 0; j < 4; ++j) {
        int reg  = g2*4 + j;
        int qrow = j + 8*g2 + 4*hi;
        float inv = 1.0f / l_lds[w4][qrow];
        #pragma unroll
        for (int nb = 0; nb < 2; ++nb) {
          float o = oacc[nb][reg] + obuf[((((w4*2 + hi)*16 + reg)*2) + nb)*32 + lq];
          X2[(size_t)(b*1024 + q0w + qrow)*1024 + h*64 + nb*32 + lq] = (bf16_t)(o * inv);
        }
      }
  }
}

// ---------------- 6) output GEMM: out = X2 * Wot^T + bo (fp32), single-buffered ----------------
__global__ __launch_bounds__(256, 3) void k_gemm_out(
    const bf16_t* __restrict__ A, const bf16_t* __restrict__ Bt,
    const float* __restrict__ bo, float* __restrict__ C)
{
  const int L = blockIdx.x;                 // 256 = 8 XCD x 32
  const int w = (L & 7) * 32 + (L >> 3);
  const int bx = w & 7, by = w >> 3;

  __shared__ bf16_t As[128*64];
  __shared__ bf16_t Bs[128*64];

  const int tid = threadIdx.x, lane = tid & 63, wid = tid >> 6;
  const int wm = wid >> 1, wn = wid & 1;
  const int bm0 = by * 128, bn0 = bx * 128;
  const int g = lane >> 4, c = lane & 15;
  const int sr = lane >> 3, sch = lane & 7;

  f32x4 acc[4][4] = {};

  #define STAGEO(kt_)                                                            \
    { _Pragma("unroll")                                                          \
      for (int i = 0; i < 4; ++i) {                                              \
        int r  = wid*32 + i*8 + sr;                                              \
        int ca = sch ^ (r & 7);                                                  \
        load_lds16(A  + (size_t)(bm0 + r)*1024 + (size_t)(kt_)*64 + ca*8,        \
                   &As[(wid*32 + i*8)*64]);                                      \
        load_lds16(Bt + (size_t)(bn0 + r)*1024 + (size_t)(kt_)*64 + ca*8,        \
                   &Bs[(wid*32 + i*8)*64]);                                      \
      } }

  for (int kt = 0; kt < 16; ++kt) {
    STAGEO(kt);
    __syncthreads();
    #pragma unroll
    for (int kk = 0; kk < 2; ++kk) {
      bf16x8 af[4], bfr[4];
      #pragma unroll
      for (int m = 0; m < 4; ++m) {
        int row = wm*64 + m*16 + c;
        int ch  = (kk*4 + g) ^ (row & 7);
        af[m] = *(const bf16x8*)&As[row*64 + ch*8];
      }
      #pragma unroll
      for (int n = 0; n < 4; ++n) {
        int row = wn*64 + n*16 + c;
        int ch  = (kk*4 + g) ^ (row & 7);
        bfr[n] = *(const bf16x8*)&Bs[row*64 + ch*8];
      }
      #pragma unroll
      for (int m = 0; m < 4; ++m)
        #pragma unroll
        for (int n = 0; n < 4; ++n)
          acc[m][n] = __builtin_amdgcn_mfma_f32_16x16x32_bf16(af[m], bfr[n], acc[m][n], 0, 0, 0);
    }
    __syncthreads();
  }
  #undef STAGEO

  #pragma unroll
  for (int n = 0; n < 4; ++n) {
    int col = bn0 + wn*64 + n*16 + c;
    float bn_ = bo[col];
    #pragma unroll
    for (int m = 0; m < 4; ++m) {
      int row0 = bm0 + wm*64 + m*16 + g*4;
      #pragma unroll
      for (int r = 0; r < 4; ++r)
        C[(size_t)(row0 + r)*1024 + col] = acc[m][n][r] + bn_;
    }
  }
}

extern "C" void kernel_launch(void* const* d_in, const int* in_sizes, int n_in,
                              void* d_out, int out_size, void* d_ws, size_t ws_size,
                              hipStream_t stream) {
  const float* iq   = (const float*)d_in[0];
  const float* ikv  = (const float*)d_in[1];
  const float* pq   = (const float*)d_in[2];
  const float* pk   = (const float*)d_in[3];
  const float* pv   = (const float*)d_in[4];
  const float* mask = (const float*)d_in[5];
  const float* wq   = (const float*)d_in[6];
  const float* bq   = (const float*)d_in[7];
  const float* wk   = (const float*)d_in[8];
  const float* bk   = (const float*)d_in[9];
  const float* wv   = (const float*)d_in[10];
  const float* bv   = (const float*)d_in[11];
  const float* wo   = (const float*)d_in[12];
  const float* bo   = (const float*)d_in[13];
  float* out = (float*)d_out;

  char* ws = (char*)d_ws;
  bf16_t* Xq  = (bf16_t*)(ws + (size_t)( 0u<<20));
  bf16_t* Xk  = (bf16_t*)(ws + (size_t)( 8u<<20));
  bf16_t* Xv  = (bf16_t*)(ws + (size_t)(16u<<20));
  bf16_t* Wt  = (bf16_t*)(ws + (size_t)(24u<<20));   // Wqt|Wkt|Wvt contiguous (3072 x 1024)
  bf16_t* Wot = (bf16_t*)(ws + (size_t)(30u<<20));
  bf16_t* Q   = (bf16_t*)(ws + (size_t)(32u<<20));
  bf16_t* K   = (bf16_t*)(ws + (size_t)(40u<<20));
  bf16_t* Vt  = (bf16_t*)(ws + (size_t)(56u<<20));
  bf16_t* X2  = (bf16_t*)(ws + (size_t)(64u<<20));

  k_prep_w<<<3072, 256, 0, stream>>>(iq, ikv, pq, pk, pv, wq, wk, wv, wo,
                                     Xq, Xk, Xv, Wt, Wot);
  k_gemm_qkv<<<768, 256, 0, stream>>>(Xq, Xk, Xv, Wt, bq, bk, bv, Q, K, Vt);
  k_attn2<<<512, 512, 0, stream>>>(Q, K, Vt, mask, X2);
  k_gemm_out<<<256, 256, 0, stream>>>(X2, Wot, bo, out);
}